// Round 7
// baseline (451.744 us; speedup 1.0000x reference)
//
#include <hip/hip_runtime.h>
#include <hip/hip_bf16.h>

#define N_NODES 100000
#define N_EDGES 800000
#define D 128
#define NH 8
#define NB ((N_NODES + 255) / 256)   // 391 blocks; NB*256 = 100096 threads

typedef __hip_bfloat16 bf16;
typedef __bf16 bf16x8 __attribute__((ext_vector_type(8)));
typedef float  f32x4  __attribute__((ext_vector_type(4)));

__device__ __forceinline__ unsigned short f2bu(float x) {
    bf16 b = __float2bfloat16(x);
    return *reinterpret_cast<unsigned short*>(&b);
}
__device__ __forceinline__ float bu2f(unsigned short u) {
    return __uint_as_float(((unsigned)u) << 16);
}
__device__ __forceinline__ float bfe0(unsigned u) { return __uint_as_float(u << 16); }
__device__ __forceinline__ float bfe1(unsigned u) { return __uint_as_float(u & 0xffff0000u); }

union frag_u { unsigned short u[8]; bf16x8 v; };

// ---------------------------------------------------------------------------
// Kernel 1: Wf prep (MFMA B-fragment layout, bf16 hi/lo split) + zero the
// CSR count array and the grid-barrier counters.  391 blocks x 256.
// ---------------------------------------------------------------------------
__global__ __launch_bounds__(256) void prep_zero(
    const float* __restrict__ Wq, const float* __restrict__ Wk, const float* __restrict__ Wv,
    unsigned short* __restrict__ Wf, int* __restrict__ counts, int* __restrict__ bars)
{
    int t = blockIdx.x * 256 + threadIdx.x;
    if (t < N_NODES) counts[t] = 0;
    if (t < 8) bars[t] = 0;
    if (t < 3 * 32 * 64) {
        int lane = t & 63;
        int ct   = (t >> 6) & 31;
        int mat  = t >> 11;
        const float* W = (mat == 0) ? Wq : (mat == 1) ? Wk : Wv;
        int c  = ct >> 3, tt = ct & 7;
        int n  = tt * 16 + (lane & 15);
        int kb = c * 32 + (lane >> 4) * 8;
        unsigned short* dst = Wf + (size_t)mat * 32768 + (size_t)ct * 1024 + (size_t)lane * 8;
#pragma unroll
        for (int j = 0; j < 8; ++j) {
            float w  = W[(size_t)(kb + j) * D + n];
            unsigned short hb = f2bu(w);
            float lo = w - bu2f(hb);
            dst[j]       = hb;          // hi (part 0)
            dst[512 + j] = f2bu(lo);    // lo (part 1)
        }
    }
}

// ---------------------------------------------------------------------------
// Kernel 2: fused Q/K/V projection via bf16 MFMA with hi/lo precision split.
// (round-5 proven version: separate Q, K, V outputs)
// ---------------------------------------------------------------------------
__global__ __launch_bounds__(256) void qkv_mfma(
    const float* __restrict__ E, const unsigned short* __restrict__ Wf,
    bf16* __restrict__ Q, bf16* __restrict__ K, bf16* __restrict__ V)
{
    __shared__ unsigned short bsh[16384];   // 32 KB: B staging, then epilogue
    const int tid  = threadIdx.x;
    const int wave = tid >> 6;
    const int lane = tid & 63;
    const int r0w  = blockIdx.x * 128 + wave * 32;   // this wave's 32 rows

    const int am = lane & 15;    // A row within 16-tile
    const int aq = lane >> 4;    // k quad

    frag_u ahi[2][4], alo[2][4];
#pragma unroll
    for (int rt = 0; rt < 2; ++rt) {
        int row = r0w + rt * 16 + am;
        if (row >= N_NODES) row = N_NODES - 1;     // clamp; stores are guarded
        const float* erow = E + (size_t)row * D + aq * 8;
#pragma unroll
        for (int c = 0; c < 4; ++c) {
            float4 e0 = *reinterpret_cast<const float4*>(erow + c * 32);
            float4 e1 = *reinterpret_cast<const float4*>(erow + c * 32 + 4);
            float ef[8] = {e0.x, e0.y, e0.z, e0.w, e1.x, e1.y, e1.z, e1.w};
#pragma unroll
            for (int j = 0; j < 8; ++j) {
                unsigned short hb = f2bu(ef[j]);
                ahi[rt][c].u[j] = hb;
                alo[rt][c].u[j] = f2bu(ef[j] - bu2f(hb));
            }
        }
    }

    bf16* const Os[3] = {Q, K, V};

#pragma unroll
    for (int mat = 0; mat < 3; ++mat) {
        f32x4 acc[8][2];
#pragma unroll
        for (int t = 0; t < 8; ++t)
#pragma unroll
            for (int rt = 0; rt < 2; ++rt)
                acc[t][rt] = (f32x4){0.f, 0.f, 0.f, 0.f};

        const unsigned short* wm = Wf + (size_t)mat * 32768;

#pragma unroll
        for (int half = 0; half < 2; ++half) {
            __syncthreads();    // previous users of bsh are done
            const uint4* src = reinterpret_cast<const uint4*>(wm + half * 16384);
            uint4* dstv = reinterpret_cast<uint4*>(bsh);
#pragma unroll
            for (int k = 0; k < 8; ++k)
                dstv[k * 256 + tid] = src[k * 256 + tid];
            __syncthreads();

#pragma unroll
            for (int t = 0; t < 8; ++t) {
#pragma unroll
                for (int cc = 0; cc < 2; ++cc) {
                    const unsigned short* bp = bsh + (cc * 8 + t) * 1024 + lane * 8;
                    bf16x8 bhi = *reinterpret_cast<const bf16x8*>(bp);
                    bf16x8 blo = *reinterpret_cast<const bf16x8*>(bp + 512);
                    const int c = half * 2 + cc;
#pragma unroll
                    for (int rt = 0; rt < 2; ++rt) {
                        acc[t][rt] = __builtin_amdgcn_mfma_f32_16x16x32_bf16(alo[rt][c].v, bhi, acc[t][rt], 0, 0, 0);
                        acc[t][rt] = __builtin_amdgcn_mfma_f32_16x16x32_bf16(ahi[rt][c].v, blo, acc[t][rt], 0, 0, 0);
                        acc[t][rt] = __builtin_amdgcn_mfma_f32_16x16x32_bf16(ahi[rt][c].v, bhi, acc[t][rt], 0, 0, 0);
                    }
                }
            }
        }
        __syncthreads();   // all waves done reading B; bsh reusable per-wave

        unsigned short* ob = bsh + wave * 2176;   // 16 rows x 136
#pragma unroll
        for (int rt = 0; rt < 2; ++rt) {
#pragma unroll
            for (int t = 0; t < 8; ++t)
#pragma unroll
                for (int r = 0; r < 4; ++r)
                    ob[(aq * 4 + r) * 136 + t * 16 + am] = f2bu(acc[t][rt][r]);
            const int row = lane >> 2, c4 = lane & 3;
            int grow = r0w + rt * 16 + row;
            if (grow < N_NODES) {
                const uint4* srcb = reinterpret_cast<const uint4*>(ob + row * 136 + c4 * 32);
                uint4 d0 = srcb[0], d1 = srcb[1], d2 = srcb[2], d3 = srcb[3];
                uint4* dst = reinterpret_cast<uint4*>(Os[mat] + (size_t)grow * D + c4 * 32);
                dst[0] = d0; dst[1] = d1; dst[2] = d2; dst[3] = d3;
            }
        }
    }
}

// ---------------------------------------------------------------------------
// Kernel 3: full CSR build in ONE kernel: histogram -> two-level scan ->
// scatter, with resident-grid spin barriers.  391 blocks x 256 threads, all
// co-resident (tiny LDS/VGPR), so spinning is deadlock-free.  Barrier
// counters are zeroed by prep_zero every launch (graph-replay safe).
// ---------------------------------------------------------------------------
__device__ __forceinline__ void gridbar(int* bar) {
    __syncthreads();
    if (threadIdx.x == 0) {
        __hip_atomic_fetch_add(bar, 1, __ATOMIC_ACQ_REL, __HIP_MEMORY_SCOPE_AGENT);
        while (__hip_atomic_load(bar, __ATOMIC_ACQUIRE, __HIP_MEMORY_SCOPE_AGENT) < NB)
            __builtin_amdgcn_s_sleep(2);
    }
    __syncthreads();
}

__global__ __launch_bounds__(256) void csr_build(
    const int* __restrict__ rows, const int* __restrict__ cols,
    int* __restrict__ counts, int* __restrict__ offsets, int* __restrict__ cursor,
    int* __restrict__ block_sums, int* __restrict__ block_pref,
    int* __restrict__ csr_cols, int* __restrict__ bars)
{
    const int tid = threadIdx.x;
    const int b   = blockIdx.x;
    const int gt  = b * 256 + tid;
    __shared__ int s[256];
    __shared__ int s2[256];
    __shared__ int bpref_sh;

    // Phase A: histogram (grid-stride over edges).
    for (int e = gt; e < N_EDGES; e += NB * 256)
        atomicAdd(&counts[rows[e]], 1);
    gridbar(&bars[0]);

    // Phase B: per-block inclusive scan of 256 counts.
    int v = (gt < N_NODES)
        ? __hip_atomic_load(&counts[gt], __ATOMIC_RELAXED, __HIP_MEMORY_SCOPE_AGENT)
        : 0;
    s[tid] = v;
    __syncthreads();
#pragma unroll
    for (int off = 1; off < 256; off <<= 1) {
        int t2 = (tid >= off) ? s[tid - off] : 0;
        __syncthreads();
        s[tid] += t2;
        __syncthreads();
    }
    int excl = s[tid] - v;          // exclusive within block
    if (tid == 255) block_sums[b] = s[255];
    gridbar(&bars[1]);

    // Phase C: block 0 scans the NB block sums (two 256-wide scans).
    if (b == 0) {
        int va = (tid < NB)
            ? __hip_atomic_load(&block_sums[tid], __ATOMIC_RELAXED, __HIP_MEMORY_SCOPE_AGENT) : 0;
        int vb = (tid + 256 < NB)
            ? __hip_atomic_load(&block_sums[tid + 256], __ATOMIC_RELAXED, __HIP_MEMORY_SCOPE_AGENT) : 0;
        s[tid] = va; s2[tid] = vb;
        __syncthreads();
#pragma unroll
        for (int off = 1; off < 256; off <<= 1) {
            int ta = (tid >= off) ? s[tid - off] : 0;
            int tb = (tid >= off) ? s2[tid - off] : 0;
            __syncthreads();
            s[tid] += ta; s2[tid] += tb;
            __syncthreads();
        }
        int totala = s[255];
        block_pref[tid] = s[tid] - va;                       // exclusive
        if (tid + 256 < NB) block_pref[tid + 256] = totala + s2[tid] - vb;
    }
    gridbar(&bars[2]);

    // Phase D: final offsets + cursor.
    if (tid == 0)
        bpref_sh = __hip_atomic_load(&block_pref[b], __ATOMIC_RELAXED, __HIP_MEMORY_SCOPE_AGENT);
    __syncthreads();
    int o = excl + bpref_sh;
    if (gt < N_NODES) { offsets[gt] = o; cursor[gt] = o; }
    gridbar(&bars[3]);

    // Phase E: scatter (grid-stride over edges).
    for (int e = gt; e < N_EDGES; e += NB * 256) {
        int pos = atomicAdd(&cursor[rows[e]], 1);
        csr_cols[pos] = cols[e];
    }
}

// ---------------------------------------------------------------------------
// Kernel 4: fused per-node attention + residual + LayerNorm.  One wave per
// node, lane owns 2 dims, edge loop unrolled x2.  (round-5 proven version)
// ---------------------------------------------------------------------------
__global__ __launch_bounds__(256) void fused_node(
    const bf16* __restrict__ Qb, const bf16* __restrict__ Kb, const bf16* __restrict__ Vb,
    const int* __restrict__ offsets, const int* __restrict__ counts,
    const int* __restrict__ csr_cols,
    const float* __restrict__ emb,
    const float* __restrict__ gamma, const float* __restrict__ beta,
    float* __restrict__ out)
{
    int n = blockIdx.x * 4 + (threadIdx.x >> 6);
    int lane = threadIdx.x & 63;
    if (n >= N_NODES) return;

    unsigned qu = *reinterpret_cast<const unsigned*>(Qb + (size_t)n * D + lane * 2);
    float q0 = bfe0(qu), q1 = bfe1(qu);

    int start = offsets[n];
    int cnt   = counts[n];

    const bf16* kbase = Kb + lane * 2;
    const bf16* vbase = Vb + lane * 2;

    float acc0 = 0.f, acc1 = 0.f, nrm = 0.f;
    for (int base = 0; base < cnt; base += 64) {
        int m = cnt - base; if (m > 64) m = 64;
        int myc = (base + lane < cnt) ? csr_cols[start + base + lane] : 0;
        int j = 0;
        for (; j + 1 < m; j += 2) {
            int c0 = __shfl(myc, j, 64);
            int c1 = __shfl(myc, j + 1, 64);
            unsigned ku0 = *reinterpret_cast<const unsigned*>(kbase + (size_t)c0 * D);
            unsigned vu0 = *reinterpret_cast<const unsigned*>(vbase + (size_t)c0 * D);
            unsigned ku1 = *reinterpret_cast<const unsigned*>(kbase + (size_t)c1 * D);
            unsigned vu1 = *reinterpret_cast<const unsigned*>(vbase + (size_t)c1 * D);
            float p0 = q0 * bfe0(ku0) + q1 * bfe1(ku0);
            float p1 = q0 * bfe0(ku1) + q1 * bfe1(ku1);
            p0 += __shfl_xor(p0, 1, 64);
            p1 += __shfl_xor(p1, 1, 64);
            p0 += __shfl_xor(p0, 2, 64);
            p1 += __shfl_xor(p1, 2, 64);
            p0 += __shfl_xor(p0, 4, 64);
            p1 += __shfl_xor(p1, 4, 64);
            float s0 = __expf(fminf(fmaxf(p0, -10.f), 10.f));
            float s1 = __expf(fminf(fmaxf(p1, -10.f), 10.f));
            nrm  += s0 + s1;
            acc0 += s0 * bfe0(vu0) + s1 * bfe0(vu1);
            acc1 += s0 * bfe1(vu0) + s1 * bfe1(vu1);
        }
        if (j < m) {
            int c0 = __shfl(myc, j, 64);
            unsigned ku0 = *reinterpret_cast<const unsigned*>(kbase + (size_t)c0 * D);
            unsigned vu0 = *reinterpret_cast<const unsigned*>(vbase + (size_t)c0 * D);
            float p0 = q0 * bfe0(ku0) + q1 * bfe1(ku0);
            p0 += __shfl_xor(p0, 1, 64);
            p0 += __shfl_xor(p0, 2, 64);
            p0 += __shfl_xor(p0, 4, 64);
            float s0 = __expf(fminf(fmaxf(p0, -10.f), 10.f));
            nrm  += s0;
            acc0 += s0 * bfe0(vu0);
            acc1 += s0 * bfe1(vu0);
        }
    }

    float w = 1.f / (nrm + 1e-8f);
    float2 e2 = *reinterpret_cast<const float2*>(emb + (size_t)n * D + lane * 2);
    float x0 = acc0 * w + e2.x;
    float x1 = acc1 * w + e2.y;

    float ssum = x0 + x1;
#pragma unroll
    for (int off = 32; off; off >>= 1) ssum += __shfl_xor(ssum, off, 64);
    float mean = ssum * (1.0f / 128.0f);
    float d0 = x0 - mean, d1 = x1 - mean;
    float var = d0 * d0 + d1 * d1;
#pragma unroll
    for (int off = 32; off; off >>= 1) var += __shfl_xor(var, off, 64);
    float rs = rsqrtf(var * (1.0f / 128.0f) + 1e-6f);

    float2 g2 = *reinterpret_cast<const float2*>(gamma + lane * 2);
    float2 b2 = *reinterpret_cast<const float2*>(beta + lane * 2);
    float2 o2 = make_float2(d0 * rs * g2.x + b2.x, d1 * rs * g2.y + b2.y);
    *reinterpret_cast<float2*>(out + (size_t)n * D + lane * 2) = o2;
}

// ---------------------------------------------------------------------------
extern "C" void kernel_launch(void* const* d_in, const int* in_sizes, int n_in,
                              void* d_out, int out_size, void* d_ws, size_t ws_size,
                              hipStream_t stream)
{
    const float* emb   = (const float*)d_in[0];
    const float* qW    = (const float*)d_in[1];
    const float* kW    = (const float*)d_in[2];
    const float* vW    = (const float*)d_in[3];
    const float* gamma = (const float*)d_in[4];
    const float* beta  = (const float*)d_in[5];
    const int*   eidx  = (const int*)d_in[6];
    const int*   rows  = eidx;
    const int*   cols  = eidx + N_EDGES;
    float* out = (float*)d_out;

    const size_t ND = (size_t)N_NODES * D;
    bf16* Qb = (bf16*)d_ws;
    bf16* Kb = Qb + ND;
    bf16* Vb = Kb + ND;
    int* counts     = (int*)(Vb + ND);
    int* offsets    = counts + N_NODES;
    int* cursor     = offsets + N_NODES;
    int* block_sums = cursor + N_NODES;
    int* block_pref = block_sums + 512;
    int* bars       = block_pref + 512;
    int* csr_cols   = bars + 8;
    unsigned short* Wf = (unsigned short*)(csr_cols + N_EDGES);  // 3*32768 ushort

    prep_zero<<<NB, 256, 0, stream>>>(qW, kW, vW, Wf, counts, bars);
    qkv_mfma<<<(N_NODES + 127) / 128, 256, 0, stream>>>(emb, Wf, Qb, Kb, Vb);
    csr_build<<<NB, 256, 0, stream>>>(rows, cols, counts, offsets, cursor,
                                      block_sums, block_pref, csr_cols, bars);
    fused_node<<<(N_NODES + 3) / 4, 256, 0, stream>>>(
        Qb, Kb, Vb, offsets, counts, csr_cols, emb, gamma, beta, out);
}